// Round 1
// baseline (9689.789 us; speedup 1.0000x reference)
//
#include <hip/hip_runtime.h>

#define TT 128
#define BB 64
#define HH 2048
#define VV 10000
#define VP 10048

typedef __attribute__((ext_vector_type(8))) short s16x8;
typedef __attribute__((ext_vector_type(4))) float f32x4;

#define MFMA(a,b,c) __builtin_amdgcn_mfma_f32_16x16x32_bf16((a),(b),(c),0,0,0)

static __device__ __forceinline__ short f2bf(float x){
  unsigned u = __float_as_uint(x);
  u += 0x7fffu + ((u>>16)&1u);
  return (short)(u>>16);
}
static __device__ __forceinline__ float bf2f(short b){
  return __uint_as_float(((unsigned)(unsigned short)b)<<16);
}

// Swizzled fragment layout for an [N,K] matrix used as MFMA B-operand (or [M,K] as A):
//   idx = ((nt*KC + kc)*64 + lane)*8 + j,  row = nt*16+(lane&15), k = kc*32+(lane>>4)*8+j
// -> a wave's fragment load is 64 lanes x 16B contiguous.

// ---------- split W0 into x-part / h-part, hi/lo bf16, swizzled (KC=64 each) ----------
__global__ __launch_bounds__(256) void k_split_w0(
    const float* __restrict__ W0,
    short* __restrict__ WxHi, short* __restrict__ WxLo,
    short* __restrict__ WhHi, short* __restrict__ WhLo){
  int tid = blockIdx.x*256 + threadIdx.x;     // 2048*512 threads
  int row = tid >> 9;
  int c8  = (tid & 511) << 3;
  const float4* s = (const float4*)(W0 + (size_t)row*4096 + c8);
  float4 f0 = s[0], f1 = s[1];
  float v[8] = {f0.x,f0.y,f0.z,f0.w,f1.x,f1.y,f1.z,f1.w};
  short hs[8], lsv[8];
#pragma unroll
  for(int j=0;j<8;j++){ hs[j]=f2bf(v[j]); lsv[j]=f2bf(v[j]-bf2f(hs[j])); }
  int isH = (c8 >= 2048);
  int k = c8 - (isH ? 2048 : 0);
  short* dh = isH ? WhHi : WxHi;
  short* dl = isH ? WhLo : WxLo;
  int nt = row>>4, kc = k>>5, ln = (row&15) | (((k>>3)&3)<<4);
  size_t base = ((size_t)(nt*64 + kc)*64 + ln)*8;
  *(s16x8*)(dh+base) = *(s16x8*)hs;
  *(s16x8*)(dl+base) = *(s16x8*)lsv;
}

// ---------- split W1 (K=4096, KC=128) ----------
__global__ __launch_bounds__(256) void k_split_w1(
    const float* __restrict__ W1,
    short* __restrict__ WHi, short* __restrict__ WLo){
  int tid = blockIdx.x*256 + threadIdx.x;
  int row = tid >> 9;
  int c8  = (tid & 511) << 3;
  const float4* s = (const float4*)(W1 + (size_t)row*4096 + c8);
  float4 f0 = s[0], f1 = s[1];
  float v[8] = {f0.x,f0.y,f0.z,f0.w,f1.x,f1.y,f1.z,f1.w};
  short hs[8], lsv[8];
#pragma unroll
  for(int j=0;j<8;j++){ hs[j]=f2bf(v[j]); lsv[j]=f2bf(v[j]-bf2f(hs[j])); }
  int nt = row>>4, kc = c8>>5, ln = (row&15) | (((c8>>3)&3)<<4);
  size_t base = ((size_t)(nt*128 + kc)*64 + ln)*8;
  *(s16x8*)(WHi+base) = *(s16x8*)hs;
  *(s16x8*)(WLo+base) = *(s16x8*)lsv;
}

// ---------- Wout -> single bf16, swizzled, zero-padded to 10048 rows ----------
__global__ __launch_bounds__(256) void k_conv_wout(
    const float* __restrict__ Wout, short* __restrict__ Wo){
  int row = blockIdx.x;             // 0..10047
  int k = threadIdx.x << 3;
  short hs[8];
  if(row < VV){
    const float4* s = (const float4*)(Wout + (size_t)row*2048 + k);
    float4 f0 = s[0], f1 = s[1];
    float v[8] = {f0.x,f0.y,f0.z,f0.w,f1.x,f1.y,f1.z,f1.w};
#pragma unroll
    for(int j=0;j<8;j++) hs[j]=f2bf(v[j]);
  } else {
#pragma unroll
    for(int j=0;j<8;j++) hs[j]=0;
  }
  int nt = row>>4, kc = k>>5, ln = (row&15) | (((k>>3)&3)<<4);
  size_t base = ((size_t)(nt*64 + kc)*64 + ln)*8;
  *(s16x8*)(Wo+base) = *(s16x8*)hs;
}

// ---------- init h state (parity 0) from `hidden` input ----------
__global__ __launch_bounds__(256) void k_init(
    const float* __restrict__ hid,
    float* __restrict__ h0f, float* __restrict__ h1f,
    short* __restrict__ h0Hi, short* __restrict__ h0Lo,
    short* __restrict__ h1Hi, short* __restrict__ h1Lo){
  int tid = blockIdx.x*256 + threadIdx.x;   // 32768
  int l = tid >> 14;
  int r = tid & 16383;
  int m = r >> 8;
  int k = (r & 255) << 3;
  const float* s = hid + ((size_t)l*BB + m)*HH + k;
  float v[8];
#pragma unroll
  for(int j=0;j<8;j++) v[j]=s[j];
  float* df = l ? h1f : h0f;
  short* dh = l ? h1Hi : h0Hi;
  short* dl = l ? h1Lo : h0Lo;
#pragma unroll
  for(int j=0;j<8;j++) df[(size_t)m*HH + k + j] = v[j];
  short hs[8], lsv[8];
#pragma unroll
  for(int j=0;j<8;j++){ hs[j]=f2bf(v[j]); lsv[j]=f2bf(v[j]-bf2f(hs[j])); }
  int mt = m>>4, kc = k>>5, ln = (m&15) | (((k>>3)&3)<<4);
  size_t base = ((size_t)(mt*64 + kc)*64 + ln)*8;
  *(s16x8*)(dh+base) = *(s16x8*)hs;
  *(s16x8*)(dl+base) = *(s16x8*)lsv;
}

// ---------- Phase A: P0 = gather(emb)[8192,2048] @ Wx0^T + b0  (hi/lo 3-product) ----------
__global__ __launch_bounds__(256) void k_gemmA(
    const int* __restrict__ toks, const float* __restrict__ emb,
    const short* __restrict__ WxHi, const short* __restrict__ WxLo,
    const float* __restrict__ b0, float* __restrict__ P0){
  __shared__ short aHi[2][2048];
  __shared__ short aLo[2][2048];
  int bx = blockIdx.x, by = blockIdx.y;
  int tid = threadIdx.x, w = tid>>6, ln = tid&63;
  int srow = w*16 + (ln&15);
  int tok = toks[by*64 + srow];
  const float* rowp = emb + (size_t)tok*2048 + ((ln>>4)<<3);
  int nt = bx*4 + w;
  f32x4 acc[4] = {{0,0,0,0},{0,0,0,0},{0,0,0,0},{0,0,0,0}};
  for(int kc=0;kc<64;kc++){
    int p = kc&1;
    const float4* sp = (const float4*)(rowp + kc*32);
    float4 f0 = sp[0], f1 = sp[1];
    float v[8] = {f0.x,f0.y,f0.z,f0.w,f1.x,f1.y,f1.z,f1.w};
    short hs[8], lsv[8];
#pragma unroll
    for(int j=0;j<8;j++){ hs[j]=f2bf(v[j]); lsv[j]=f2bf(v[j]-bf2f(hs[j])); }
    *(s16x8*)&aHi[p][tid*8] = *(s16x8*)hs;
    *(s16x8*)&aLo[p][tid*8] = *(s16x8*)lsv;
    __syncthreads();
    size_t bidx = ((size_t)(nt*64 + kc)*64 + ln)*8;
    s16x8 bh = *(const s16x8*)(WxHi + bidx);
    s16x8 bl = *(const s16x8*)(WxLo + bidx);
#pragma unroll
    for(int mt=0;mt<4;mt++){
      s16x8 ah = *(const s16x8*)&aHi[p][(mt*64+ln)*8];
      s16x8 al = *(const s16x8*)&aLo[p][(mt*64+ln)*8];
      acc[mt] = MFMA(ah,bh,acc[mt]);
      acc[mt] = MFMA(al,bh,acc[mt]);
      acc[mt] = MFMA(ah,bl,acc[mt]);
    }
  }
  int nl = ln&15;
  int n = bx*64 + w*16 + nl;
  float bias = b0[n];
  int r0 = (ln>>4)*4;
#pragma unroll
  for(int mt=0;mt<4;mt++){
#pragma unroll
    for(int r=0;r<4;r++){
      int m = by*64 + mt*16 + r0 + r;
      P0[(size_t)m*HH + n] = acc[mt][r] + bias;
    }
  }
}

// ---------- per-step layer 0: h0' = tanh(P0[t] + h0 @ Wh0^T), hi/lo ----------
__global__ __launch_bounds__(256) void k_step_l0(
    const short* __restrict__ AHi, const short* __restrict__ ALo,
    const short* __restrict__ WhHi, const short* __restrict__ WhLo,
    const float* __restrict__ P0t,
    float* __restrict__ hfN, short* __restrict__ hHiN, short* __restrict__ hLoN){
  __shared__ float red[4][64][16];
  int nt = blockIdx.x;
  int tid = threadIdx.x, w = tid>>6, ln = tid&63;
  f32x4 acc[4] = {{0,0,0,0},{0,0,0,0},{0,0,0,0},{0,0,0,0}};
  for(int i=0;i<16;i++){
    int kc = w*16 + i;
    size_t bidx = ((size_t)(nt*64 + kc)*64 + ln)*8;
    s16x8 bh = *(const s16x8*)(WhHi + bidx);
    s16x8 bl = *(const s16x8*)(WhLo + bidx);
#pragma unroll
    for(int mt=0;mt<4;mt++){
      size_t aidx = ((size_t)(mt*64 + kc)*64 + ln)*8;
      s16x8 ah = *(const s16x8*)(AHi + aidx);
      s16x8 al = *(const s16x8*)(ALo + aidx);
      acc[mt] = MFMA(ah,bh,acc[mt]);
      acc[mt] = MFMA(al,bh,acc[mt]);
      acc[mt] = MFMA(ah,bl,acc[mt]);
    }
  }
#pragma unroll
  for(int mt=0;mt<4;mt++)
#pragma unroll
    for(int r=0;r<4;r++)
      red[w][mt*16 + (ln>>4)*4 + r][ln&15] = acc[mt][r];
  __syncthreads();
  int m = tid>>2, nl0 = (tid&3)*4;
#pragma unroll
  for(int i=0;i<4;i++){
    int nl = nl0 + i, n = nt*16 + nl;
    float s = red[0][m][nl]+red[1][m][nl]+red[2][m][nl]+red[3][m][nl];
    float val = tanhf(s + P0t[(size_t)m*HH + n]);
    hfN[(size_t)m*HH + n] = val;
    short hi = f2bf(val), lo = f2bf(val - bf2f(hi));
    int mt = m>>4, kc = n>>5, ln2 = (m&15) | (((n>>3)&3)<<4), j = n&7;
    size_t idx = ((size_t)(mt*64 + kc)*64 + ln2)*8 + j;
    hHiN[idx] = hi; hLoN[idx] = lo;
  }
}

// ---------- per-step layer 1: h1' = tanh([h0',h1] @ W1^T + b1), hi/lo; emits bf16 H1[t] ----------
__global__ __launch_bounds__(256) void k_step_l1(
    const short* __restrict__ h0Hi, const short* __restrict__ h0Lo,   // new h0
    const short* __restrict__ h1Hi, const short* __restrict__ h1Lo,   // old h1
    const short* __restrict__ W1Hi, const short* __restrict__ W1Lo,
    const float* __restrict__ b1,
    float* __restrict__ hfN, short* __restrict__ hHiN, short* __restrict__ hLoN,
    short* __restrict__ H1t){
  __shared__ float red[4][64][16];
  int nt = blockIdx.x;
  int tid = threadIdx.x, w = tid>>6, ln = tid&63;
  const short* aHiB = (w<2) ? h0Hi : h1Hi;
  const short* aLoB = (w<2) ? h0Lo : h1Lo;
  int kc0 = (w&1)*32;
  f32x4 acc[4] = {{0,0,0,0},{0,0,0,0},{0,0,0,0},{0,0,0,0}};
  for(int i=0;i<32;i++){
    int kcl = kc0 + i;
    int kcg = w*32 + i;
    size_t bidx = ((size_t)(nt*128 + kcg)*64 + ln)*8;
    s16x8 bh = *(const s16x8*)(W1Hi + bidx);
    s16x8 bl = *(const s16x8*)(W1Lo + bidx);
#pragma unroll
    for(int mt=0;mt<4;mt++){
      size_t aidx = ((size_t)(mt*64 + kcl)*64 + ln)*8;
      s16x8 ah = *(const s16x8*)(aHiB + aidx);
      s16x8 al = *(const s16x8*)(aLoB + aidx);
      acc[mt] = MFMA(ah,bh,acc[mt]);
      acc[mt] = MFMA(al,bh,acc[mt]);
      acc[mt] = MFMA(ah,bl,acc[mt]);
    }
  }
#pragma unroll
  for(int mt=0;mt<4;mt++)
#pragma unroll
    for(int r=0;r<4;r++)
      red[w][mt*16 + (ln>>4)*4 + r][ln&15] = acc[mt][r];
  __syncthreads();
  int m = tid>>2, nl0 = (tid&3)*4;
#pragma unroll
  for(int i=0;i<4;i++){
    int nl = nl0 + i, n = nt*16 + nl;
    float s = red[0][m][nl]+red[1][m][nl]+red[2][m][nl]+red[3][m][nl];
    float val = tanhf(s + b1[n]);
    hfN[(size_t)m*HH + n] = val;
    short hi = f2bf(val), lo = f2bf(val - bf2f(hi));
    int mt = m>>4, kc = n>>5, ln2 = (m&15) | (((n>>3)&3)<<4), j = n&7;
    size_t idx = ((size_t)(mt*64 + kc)*64 + ln2)*8 + j;
    hHiN[idx] = hi; hLoN[idx] = lo;
    H1t[idx] = hi;
  }
}

// ---------- Phase C: logits = H1[8192,2048] @ Wout^T + bout  (plain bf16) ----------
__global__ __launch_bounds__(256) void k_gemmC(
    const short* __restrict__ H1s, const short* __restrict__ Wo,
    const float* __restrict__ bout, float* __restrict__ outp){
  __shared__ short aB[2][2048];
  int bx = blockIdx.x, by = blockIdx.y;
  int tid = threadIdx.x, w = tid>>6, ln = tid&63;
  int nt = bx*4 + w;
  f32x4 acc[4] = {{0,0,0,0},{0,0,0,0},{0,0,0,0},{0,0,0,0}};
  for(int kc=0;kc<64;kc++){
    int p = kc&1;
    s16x8 av = *(const s16x8*)(H1s + ((size_t)((by*4+w)*64 + kc)*64 + ln)*8);
    *(s16x8*)&aB[p][tid*8] = av;
    __syncthreads();
    size_t bidx = ((size_t)(nt*64 + kc)*64 + ln)*8;
    s16x8 bh = *(const s16x8*)(Wo + bidx);
#pragma unroll
    for(int mt=0;mt<4;mt++){
      s16x8 ah = *(const s16x8*)&aB[p][(mt*64+ln)*8];
      acc[mt] = MFMA(ah,bh,acc[mt]);
    }
  }
  int n = bx*64 + w*16 + (ln&15);
  if(n < VV){
    float bias = bout[n];
    int r0 = (ln>>4)*4;
#pragma unroll
    for(int mt=0;mt<4;mt++){
#pragma unroll
      for(int r=0;r<4;r++){
        int m = by*64 + mt*16 + r0 + r;
        outp[(size_t)m*VV + n] = acc[mt][r] + bias;
      }
    }
  }
}

// ---------- final hidden copy ----------
__global__ __launch_bounds__(256) void k_final(
    const float* __restrict__ h0f, const float* __restrict__ h1f,
    float* __restrict__ dst){
  int tid = blockIdx.x*256 + threadIdx.x;    // 65536 threads, float4 each
  const float4* s = (tid < 32768) ? (const float4*)h0f : (const float4*)h1f;
  ((float4*)dst)[tid] = s[tid & 32767];
}

extern "C" void kernel_launch(void* const* d_in, const int* in_sizes, int n_in,
                              void* d_out, int out_size, void* d_ws, size_t ws_size,
                              hipStream_t stream){
  const int*   toks = (const int*)d_in[0];
  const float* hid  = (const float*)d_in[1];
  const float* emb  = (const float*)d_in[2];
  const float* W0   = (const float*)d_in[3];
  const float* b0   = (const float*)d_in[4];
  const float* W1   = (const float*)d_in[5];
  const float* b1   = (const float*)d_in[6];
  const float* Wout = (const float*)d_in[7];
  const float* bout = (const float*)d_in[8];
  float* out = (float*)d_out;

  char* ws = (char*)d_ws;
  size_t off = 0;
  auto take = [&](size_t bytes)->void*{
    void* r = ws + off; off += (bytes + 255) & ~(size_t)255; return r; };

  short* WxHi = (short*)take((size_t)2048*2048*2);
  short* WxLo = (short*)take((size_t)2048*2048*2);
  short* WhHi = (short*)take((size_t)2048*2048*2);
  short* WhLo = (short*)take((size_t)2048*2048*2);
  short* W1Hi = (short*)take((size_t)2048*4096*2);
  short* W1Lo = (short*)take((size_t)2048*4096*2);
  short* Wo   = (short*)take((size_t)VP*2048*2);
  float* P0   = (float*)take((size_t)8192*2048*4);
  short* H1s  = (short*)take((size_t)8192*2048*2);
  float *h0F[2], *h1F[2];
  short *h0Hi[2], *h0Lo[2], *h1Hi[2], *h1Lo[2];
  for(int i=0;i<2;i++){
    h0F[i]  = (float*)take((size_t)64*2048*4);
    h1F[i]  = (float*)take((size_t)64*2048*4);
    h0Hi[i] = (short*)take((size_t)64*2048*2);
    h0Lo[i] = (short*)take((size_t)64*2048*2);
    h1Hi[i] = (short*)take((size_t)64*2048*2);
    h1Lo[i] = (short*)take((size_t)64*2048*2);
  }

  k_split_w0<<<4096,256,0,stream>>>(W0, WxHi,WxLo,WhHi,WhLo);
  k_split_w1<<<4096,256,0,stream>>>(W1, W1Hi,W1Lo);
  k_conv_wout<<<VP,256,0,stream>>>(Wout, Wo);
  k_init<<<128,256,0,stream>>>(hid, h0F[0],h1F[0], h0Hi[0],h0Lo[0], h1Hi[0],h1Lo[0]);
  k_gemmA<<<dim3(32,128),256,0,stream>>>(toks, emb, WxHi, WxLo, b0, P0);

  for(int t=0;t<TT;t++){
    int p = t&1, q = p^1;
    k_step_l0<<<128,256,0,stream>>>(h0Hi[p],h0Lo[p], WhHi,WhLo,
        P0 + (size_t)t*64*2048, h0F[q],h0Hi[q],h0Lo[q]);
    k_step_l1<<<128,256,0,stream>>>(h0Hi[q],h0Lo[q], h1Hi[p],h1Lo[p],
        W1Hi,W1Lo, b1, h1F[q],h1Hi[q],h1Lo[q], H1s + (size_t)t*64*2048);
  }

  k_gemmC<<<dim3(157,128),256,0,stream>>>(H1s, Wo, bout, out);
  k_final<<<256,256,0,stream>>>(h0F[0], h1F[0], out + (size_t)8192*VV);
}